// Round 7
// baseline (76.053 us; speedup 1.0000x reference)
//
#include <hip/hip_runtime.h>
#include <float.h>

// ChamferLoss via MFMA: B=4, N=16384 src, M=4096 verts, fp32 in/out.
// loss[b] = (1/N) * sum_n min_m max(||p_bn - v_bm||^2, 0)
//
// d2 = pp + (v2 - 2 p.v). Bracket on the MATRIX pipe, split-bf16 packed into
// K=16 of mfma_f32_32x32x16_bf16 (validated R6, absmax 0.0):
//   A row (point):  [ph x3, pl x3, ph x3, 1, 1, 0...]
//   B col (vert):   [-2vh x3, -2vh x3, -2vl x3, v2h, v2l, 0...]
// Running min per C-slot across vert tiles; cross-lane min via a small
// per-wave LDS transpose. pp added in the reduce kernel.
//
// R7 structure: NO LDS staging in the main loop. B-frags (512 KB total,
// L2-resident) are read per-lane from global: 1 KB coalesced per wave-tile.
// Total B-frag L2 traffic is fixed at (BN/64)*M*32 = 128 MB (~3.7 us at
// 34.5 TB/s) regardless of chunking, so use 4 chunks -> 1024 blocks,
// 4 blocks/CU, ~4 waves/SIMD for latency hiding. Unroll 4 keeps 4 loads in
// flight at ~130 VGPRs (no spills, C/D stay in the unified VGPR file).

typedef __bf16 bf16x8 __attribute__((ext_vector_type(8)));
typedef float  f32x16 __attribute__((ext_vector_type(16)));

constexpr int B = 4, N = 16384, M = 4096;
constexpr int BN = B * N;
constexpr int NCHUNK = 4;
constexpr int CHUNK_V = M / NCHUNK;          // 1024 verts per chunk
constexpr int TILES = CHUNK_V / 32;          // 32 vert tiles per chunk
constexpr int TPB = 256;                     // 4 waves
constexpr int PPB = 256;                     // points per block (wave: 2 tiles)
constexpr int PBLK = BN / PPB;               // 256 point-blocks
constexpr size_t BFRAG_BYTES = (size_t)B * M * 32;   // 512 KB in ws

// ---- Pre-pass: build B-fragments; zero out[]. ----
// Vert m of batch b -> byte offset:
//   b*131072 + chunk*32768 + tile*1024 + khalf*512 + col*16
__global__ __launch_bounds__(256) void chamfer_pre(
    const float* __restrict__ tv, unsigned char* __restrict__ bfr,
    float* __restrict__ out)
{
    if (blockIdx.x == 0 && threadIdx.x < B) out[threadIdx.x] = 0.0f;
    int i = blockIdx.x * 256 + threadIdx.x;      // 0..B*M-1
    int b = i >> 12;                             // /M
    int m = i & (M - 1);
    float x = tv[3 * i + 0], y = tv[3 * i + 1], z = tv[3 * i + 2];
    __bf16 xh = (__bf16)x, yh = (__bf16)y, zh = (__bf16)z;
    float xhf = (float)xh, yhf = (float)yh, zhf = (float)zh;
    __bf16 xl = (__bf16)(x - xhf), yl = (__bf16)(y - yhf), zl = (__bf16)(z - zhf);
    float v2 = fmaf(x, x, fmaf(y, y, z * z));
    __bf16 v2h = (__bf16)v2;
    __bf16 v2l = (__bf16)(v2 - (float)v2h);
    __bf16 zero = (__bf16)0.0f;

    bf16x8 h0, h1;
    h0[0] = (__bf16)(-2.0f * xhf); h0[1] = (__bf16)(-2.0f * yhf);
    h0[2] = (__bf16)(-2.0f * zhf);
    h0[3] = h0[0]; h0[4] = h0[1]; h0[5] = h0[2];
    h0[6] = (__bf16)(-2.0f * (float)xl); h0[7] = (__bf16)(-2.0f * (float)yl);
    h1[0] = (__bf16)(-2.0f * (float)zl); h1[1] = v2h; h1[2] = v2l;
    h1[3] = zero; h1[4] = zero; h1[5] = zero; h1[6] = zero; h1[7] = zero;

    int chunk = m >> 10, local = m & (CHUNK_V - 1), tile = local >> 5, c = m & 31;
    size_t base = (size_t)b * 131072 + (size_t)chunk * 32768 + tile * 1024 + c * 16;
    *(bf16x8*)(bfr + base)       = h0;
    *(bf16x8*)(bfr + base + 512) = h1;
}

// ---- Main: 1024 blocks = 256 point-blocks x 4 chunks, 4 blocks/CU. ----
// Wave w owns 2 point tiles (64 pts); one global B-frag load feeds 2 MFMAs.
// partial[chunk][point] = min over chunk verts of (v2 - 2 p.v).
__global__ __launch_bounds__(TPB) void chamfer_mfma(
    const float* __restrict__ src, const unsigned char* __restrict__ bfr,
    float* __restrict__ partial)
{
    __shared__ float epi[4 * 2 * 32 * 33];       // 33.8 KB, epilogue only
    const int blk   = blockIdx.x;
    const int chunk = blk & 3;
    const int pblk  = blk >> 2;                  // 0..255
    const int b     = pblk >> 6;                 // 64 point-blocks per batch
    const int t     = threadIdx.x;
    const int w     = t >> 6, L = t & 63;
    const int half  = L >> 5, c = L & 31;

    // A-frags for this wave's two point tiles (layout validated in R6).
    const int gpa = pblk * 256 + w * 64 + c;
    const int gpb = gpa + 32;
    float ax = src[3*gpa], ay = src[3*gpa+1], az = src[3*gpa+2];
    float bx = src[3*gpb], by = src[3*gpb+1], bz = src[3*gpb+2];
    __bf16 one = (__bf16)1.0f, zero = (__bf16)0.0f;
    bf16x8 aA, aB;
    {
        __bf16 xh=(__bf16)ax, yh=(__bf16)ay, zh=(__bf16)az;
        __bf16 xl=(__bf16)(ax-(float)xh), yl=(__bf16)(ay-(float)yh), zl=(__bf16)(az-(float)zh);
        if (half == 0) { aA[0]=xh; aA[1]=yh; aA[2]=zh; aA[3]=xl; aA[4]=yl; aA[5]=zl; aA[6]=xh; aA[7]=yh; }
        else { aA[0]=zh; aA[1]=one; aA[2]=one; aA[3]=zero; aA[4]=zero; aA[5]=zero; aA[6]=zero; aA[7]=zero; }
    }
    {
        __bf16 xh=(__bf16)bx, yh=(__bf16)by, zh=(__bf16)bz;
        __bf16 xl=(__bf16)(bx-(float)xh), yl=(__bf16)(by-(float)yh), zl=(__bf16)(bz-(float)zh);
        if (half == 0) { aB[0]=xh; aB[1]=yh; aB[2]=zh; aB[3]=xl; aB[4]=yl; aB[5]=zl; aB[6]=xh; aB[7]=yh; }
        else { aB[0]=zh; aB[1]=one; aB[2]=one; aB[3]=zero; aB[4]=zero; aB[5]=zero; aB[6]=zero; aB[7]=zero; }
    }

    f32x16 mnA, mnB, zeroC;
#pragma unroll
    for (int r = 0; r < 16; ++r) { mnA[r] = FLT_MAX; mnB[r] = FLT_MAX; zeroC[r] = 0.0f; }

    // B-frag loads straight from global (L2-hot): wave reads 1 KB/tile
    // coalesced (lane -> 16 B at half*512 + c*16).
    const char* bp = (const char*)bfr + (size_t)b * 131072
                   + (size_t)chunk * 32768 + half * 512 + c * 16;
#pragma unroll 4
    for (int tl = 0; tl < TILES; ++tl) {
        bf16x8 bf = *(const bf16x8*)(bp + (size_t)tl * 1024);
        f32x16 Ca = __builtin_amdgcn_mfma_f32_32x32x16_bf16(aA, bf, zeroC, 0, 0, 0);
        f32x16 Cb = __builtin_amdgcn_mfma_f32_32x32x16_bf16(aB, bf, zeroC, 0, 0, 0);
#pragma unroll
        for (int r = 0; r < 16; ++r) {
            mnA[r] = fminf(mnA[r], Ca[r]);
            mnB[r] = fminf(mnB[r], Cb[r]);
        }
    }

    // Epilogue: C/D row = (r&3)+8*(r>>2)+4*half, col = c. Per-wave stride-33
    // transpose (conflict-free), then min across the 32 vert-classes.
    float* epw = epi + w * (2 * 32 * 33);
#pragma unroll
    for (int r = 0; r < 16; ++r) {
        int row = (r & 3) + 8 * (r >> 2) + 4 * half;
        epw[row * 33 + c]        = mnA[r];
        epw[(32 + row) * 33 + c] = mnB[r];
    }
    __syncthreads();

    // Lane L -> tile (L>>5), row (L&31) -> block point w*64 + L.
    const float* myrow = epi + w * (2 * 32 * 33) + (L >> 5) * (32 * 33) + (L & 31) * 33;
    float m = myrow[0];
#pragma unroll
    for (int k = 1; k < 32; ++k) m = fminf(m, myrow[k]);
    partial[(size_t)chunk * BN + pblk * 256 + w * 64 + L] = m;
}

// ---- Reduce: min over 4 chunks, + pp, clamp, per-batch mean. ----
__global__ __launch_bounds__(256) void chamfer_reduce(
    const float* __restrict__ partial, const float* __restrict__ src,
    float* __restrict__ out)
{
    const int p = blockIdx.x * 256 + threadIdx.x;
    const int b = blockIdx.x >> 6;               // 64 blocks per batch
    float m = fminf(fminf(partial[p], partial[(size_t)BN + p]),
                    fminf(partial[2 * (size_t)BN + p], partial[3 * (size_t)BN + p]));
    float x = src[3*p], y = src[3*p+1], z = src[3*p+2];
    float pp = fmaf(x, x, fmaf(y, y, z * z));
    float sum = fmaxf(m + pp, 0.0f);

    for (int off = 32; off > 0; off >>= 1)
        sum += __shfl_down(sum, off, 64);
    __shared__ float acc[4];
    if ((threadIdx.x & 63) == 0) acc[threadIdx.x >> 6] = sum;
    __syncthreads();
    if (threadIdx.x == 0) {
        float s = acc[0] + acc[1] + acc[2] + acc[3];
        atomicAdd(&out[b], s * (1.0f / N));
    }
}

extern "C" void kernel_launch(void* const* d_in, const int* in_sizes, int n_in,
                              void* d_out, int out_size, void* d_ws, size_t ws_size,
                              hipStream_t stream) {
    const float* src = (const float*)d_in[0];    // (B, N, 3) fp32
    const float* tv  = (const float*)d_in[1];    // (B, M, 3) fp32
    float* out = (float*)d_out;                  // (B,) fp32
    unsigned char* bfr = (unsigned char*)d_ws;   // 512 KB B-frags
    float* partial = (float*)((char*)d_ws + BFRAG_BYTES);  // 1 MB

    chamfer_pre   <<<(B * M) / 256, 256, 0, stream>>>(tv, bfr, out);
    chamfer_mfma  <<<PBLK * NCHUNK, TPB, 0, stream>>>(src, bfr, partial);
    chamfer_reduce<<<BN / 256, 256, 0, stream>>>(partial, src, out);
}